// Round 1
// baseline (830.279 us; speedup 1.0000x reference)
//
#include <hip/hip_runtime.h>
#include <hip/hip_bf16.h>
#include <stdint.h>

#define N_PTS 100000
#define INC 128
#define NSLOT 27

typedef float f32x4 __attribute__((ext_vector_type(4)));
typedef short bf16x8 __attribute__((ext_vector_type(8)));   // 8 bf16 in 4 VGPRs (guide §3)

// ---------------- workspace layout (bytes, all 256-aligned) ----------------
// Fb    : (N+1)*128 bf16   (row N = zeros, the neighbor-pad row)
// Wb    : 27*128*128 bf16  transposed to [slot][d][c]
// Wpre  : 128*128 bf16     [d][c] (== w_pre as stored)
// F_input: N*128 f32       (LN(F @ w_pre^T))
// aux   : N*384 f32        (segment sums; only multi-count cells are touched)
static const size_t OFF_FB   = 0;
static const size_t SZ_FB    = (size_t)(N_PTS + 1) * INC * 2;      // 25,600,256
static const size_t OFF_WB   = OFF_FB + SZ_FB;
static const size_t SZ_WB    = (size_t)NSLOT * INC * INC * 2;      // 884,736
static const size_t OFF_WPRE = OFF_WB + SZ_WB;
static const size_t SZ_WPRE  = (size_t)INC * INC * 2;              // 32,768
static const size_t OFF_FIN  = OFF_WPRE + SZ_WPRE;
static const size_t SZ_FIN   = (size_t)N_PTS * INC * 4;            // 51,200,000
static const size_t OFF_AUX  = OFF_FIN + SZ_FIN;                   // total ~231.3 MB

// async 16B global->LDS (per-lane global addr; LDS base wave-uniform, lane*16)
__device__ __forceinline__ void gld_lds16(const void* g, void* l) {
    __builtin_amdgcn_global_load_lds(
        (const __attribute__((address_space(1))) uint32_t*)g,
        (__attribute__((address_space(3))) uint32_t*)l, 16, 0, 0);
}

// identical in both kernels so the vox2 - F_input*pos cancellation stays ~exact
__device__ __forceinline__ float compute_pos(int c, float cx, float cy, float cz,
                                             const float* __restrict__ w_pos,
                                             const float* __restrict__ alpha) {
    const float* w = w_pos + c * 3;
    return (cx * w[0] + cy * w[1] + cz * w[2]) * alpha[c];
}

// ---------------- K0: dtype conversions (+ zero pad row, w_conv transpose) --
__global__ __launch_bounds__(256) void k_convert(
        const float* __restrict__ F, const float* __restrict__ w_pre,
        const float* __restrict__ w_conv,
        __hip_bfloat16* __restrict__ Fb, __hip_bfloat16* __restrict__ Wb,
        __hip_bfloat16* __restrict__ Wpre) {
    int i = blockIdx.x * 256 + threadIdx.x;
    const int nF  = N_PTS * INC;            // 12,800,000
    const int nF1 = nF + INC;
    const int nWp = nF1 + INC * INC;
    const int nWc = nWp + NSLOT * INC * INC;
    if (i < nF)  { Fb[i] = __float2bfloat16(F[i]); return; }
    if (i < nF1) { Fb[i] = __float2bfloat16(0.0f); return; }
    if (i < nWp) { int j = i - nF1; Wpre[j] = __float2bfloat16(w_pre[j]); return; }
    if (i < nWc) {
        int j = i - nWp;
        int k = j / (INC * INC); int rem = j % (INC * INC);
        int d = rem / INC;       int c = rem % INC;
        Wb[j] = __float2bfloat16(w_conv[(size_t)k * INC * INC + (size_t)c * INC + d]);
    }
}

// ---------------- K0b: zero aux only for multi-member coarse cells ----------
__global__ __launch_bounds__(256) void k_zero_aux(
        const float* __restrict__ counts_v, const int* __restrict__ aux_idx,
        float* __restrict__ aux) {
    int p = blockIdx.x * 256 + threadIdx.x;
    if (p >= N_PTS) return;
    if (counts_v[p] > 1.5f) {
        float4* a = (float4*)(aux + (size_t)aux_idx[p] * (3 * INC));
        for (int i = 0; i < (3 * INC) / 4; ++i) a[i] = make_float4(0.f, 0.f, 0.f, 0.f);
    }
}

// ---------------- K1: G = F @ w_pre^T (bf16 MFMA) ; epilogue: LN -> F_input,
//                  atomic segment-sum of cat for multi cells ----------------
__global__ __launch_bounds__(256) void k_pre_gemm(
        const __hip_bfloat16* __restrict__ Fb, const __hip_bfloat16* __restrict__ Wpre,
        const int* __restrict__ coords, const float* __restrict__ counts_v,
        const int* __restrict__ aux_idx, const float* __restrict__ w_pos,
        const float* __restrict__ alpha, const float* __restrict__ g_pre,
        const float* __restrict__ b_pre, float* __restrict__ F_input,
        float* __restrict__ aux) {
    __shared__ uint4 s_A[128 * 8];   // 128 rows x 8 chunks(16B), XOR-swizzled
    __shared__ uint4 s_B[128 * 8];

    const int tid = threadIdx.x, w = tid >> 6, lane = tid & 63;
    const int p0 = blockIdx.x * 128;

    f32x4 acc[2][8];
#pragma unroll
    for (int i = 0; i < 2; ++i)
#pragma unroll
        for (int j = 0; j < 8; ++j) acc[i][j] = (f32x4){0.f, 0.f, 0.f, 0.f};

#pragma unroll
    for (int kc = 0; kc < 2; ++kc) {
        __syncthreads();
#pragma unroll
        for (int t = 0; t < 4; ++t) {
            int r = (w << 5) + (t << 3) + (lane >> 3);
            int j = (lane & 7) ^ (r & 7);
            int prow = p0 + r; if (prow > N_PTS) prow = N_PTS;
            gld_lds16(Fb + ((size_t)prow * INC + kc * 64 + (j << 3)),
                      &s_A[((w << 5) + (t << 3)) * 8]);
            gld_lds16(Wpre + ((size_t)r * INC + kc * 64 + (j << 3)),
                      &s_B[((w << 5) + (t << 3)) * 8]);
        }
        __syncthreads();
        const int q = lane >> 4, l15 = lane & 15;
#pragma unroll
        for (int kk = 0; kk < 2; ++kk) {
            int jlog = (kk << 2) + q;
            bf16x8 a[2], b[8];
#pragma unroll
            for (int i = 0; i < 2; ++i) {
                int r = (w << 5) + (i << 4) + l15;
                a[i] = __builtin_bit_cast(bf16x8, s_A[r * 8 + (jlog ^ (r & 7))]);
            }
#pragma unroll
            for (int j = 0; j < 8; ++j) {
                int n = (j << 4) + l15;
                b[j] = __builtin_bit_cast(bf16x8, s_B[n * 8 + (jlog ^ (n & 7))]);
            }
#pragma unroll
            for (int i = 0; i < 2; ++i)
#pragma unroll
                for (int j = 0; j < 8; ++j)
                    acc[i][j] = __builtin_amdgcn_mfma_f32_16x16x32_bf16(a[i], b[j], acc[i][j], 0, 0, 0);
        }
    }

    // epilogue: each 16-lane group owns complete rows (all 128 channels)
    const int q = lane >> 4, l15 = lane & 15;
#pragma unroll
    for (int i = 0; i < 2; ++i) {
#pragma unroll
        for (int r = 0; r < 4; ++r) {
            int p = p0 + (w << 5) + (i << 4) + (q << 2) + r;
            if (p >= N_PTS) continue;
            float vj[8], s = 0.f, ss = 0.f;
#pragma unroll
            for (int j = 0; j < 8; ++j) { float v = acc[i][j][r]; vj[j] = v; s += v; ss += v * v; }
#pragma unroll
            for (int m = 1; m < 16; m <<= 1) { s += __shfl_xor(s, m); ss += __shfl_xor(ss, m); }
            float mean = s * (1.f / 128.f);
            float rstd = rsqrtf(ss * (1.f / 128.f) - mean * mean + 1e-6f);
            float cnt = counts_v[p];
            bool multi = cnt > 1.5f;
            float cx = (float)coords[p * 3 + 0], cy = (float)coords[p * 3 + 1],
                  cz = (float)coords[p * 3 + 2];
            float* auxp = aux + (size_t)aux_idx[p] * (3 * INC);
#pragma unroll
            for (int j = 0; j < 8; ++j) {
                int c = (j << 4) + l15;
                float fi = (vj[j] - mean) * rstd * g_pre[c] + b_pre[c];
                F_input[(size_t)p * INC + c] = fi;
                if (multi) {
                    float ps = compute_pos(c, cx, cy, cz, w_pos, alpha);
                    float sn, cs; sincosf(ps, &sn, &cs);
                    atomicAdd(auxp + c,           fi * cs);
                    atomicAdd(auxp + INC + c,     fi * sn);
                    atomicAdd(auxp + 2 * INC + c, fi * ps);
                }
            }
        }
    }
}

// ---------------- K2: 27-slot gathered conv GEMM + full fused epilogue ------
__global__ __launch_bounds__(256) void k_conv_gemm(
        const __hip_bfloat16* __restrict__ Fb, const __hip_bfloat16* __restrict__ Wb,
        const int* __restrict__ nbr_idx, const float* __restrict__ F_input,
        const float* __restrict__ aux, const int* __restrict__ coords,
        const float* __restrict__ counts_v, const int* __restrict__ aux_idx,
        const float* __restrict__ w_pos, const float* __restrict__ alpha,
        const float* __restrict__ g_local, const float* __restrict__ b_local,
        const float* __restrict__ g_norm, const float* __restrict__ b_norm,
        float* __restrict__ out) {
    __shared__ int   s_nbr[128 * NSLOT];   // 13.8 KB
    __shared__ uint4 s_A[128 * 8];         // 16 KB, XOR-swizzled gather tile
    __shared__ uint4 s_B[128 * 8];         // 16 KB

    const int tid = threadIdx.x, w = tid >> 6, lane = tid & 63;
    const int p0 = blockIdx.x * 128;

    for (int i = tid; i < 128 * NSLOT; i += 256) {
        int g = p0 * NSLOT + i;
        s_nbr[i] = (g < N_PTS * NSLOT) ? nbr_idx[g] : N_PTS;
    }

    f32x4 acc[2][8];
#pragma unroll
    for (int i = 0; i < 2; ++i)
#pragma unroll
        for (int j = 0; j < 8; ++j) acc[i][j] = (f32x4){0.f, 0.f, 0.f, 0.f};

    for (int slot = 0; slot < NSLOT; ++slot) {
#pragma unroll
        for (int kc = 0; kc < 2; ++kc) {
            __syncthreads();   // also covers the initial s_nbr fill
#pragma unroll
            for (int t = 0; t < 4; ++t) {
                int r = (w << 5) + (t << 3) + (lane >> 3);
                int j = (lane & 7) ^ (r & 7);
                int nrow = s_nbr[r * NSLOT + slot];           // broadcast read
                gld_lds16(Fb + ((size_t)nrow * INC + kc * 64 + (j << 3)),
                          &s_A[((w << 5) + (t << 3)) * 8]);
                gld_lds16(Wb + (((size_t)slot * INC + r) * INC + kc * 64 + (j << 3)),
                          &s_B[((w << 5) + (t << 3)) * 8]);
            }
            __syncthreads();
            const int q = lane >> 4, l15 = lane & 15;
#pragma unroll
            for (int kk = 0; kk < 2; ++kk) {
                int jlog = (kk << 2) + q;
                bf16x8 a[2], b[8];
#pragma unroll
                for (int i = 0; i < 2; ++i) {
                    int r = (w << 5) + (i << 4) + l15;
                    a[i] = __builtin_bit_cast(bf16x8, s_A[r * 8 + (jlog ^ (r & 7))]);
                }
#pragma unroll
                for (int j = 0; j < 8; ++j) {
                    int n = (j << 4) + l15;
                    b[j] = __builtin_bit_cast(bf16x8, s_B[n * 8 + (jlog ^ (n & 7))]);
                }
#pragma unroll
                for (int i = 0; i < 2; ++i)
#pragma unroll
                    for (int j = 0; j < 8; ++j)
                        acc[i][j] = __builtin_amdgcn_mfma_f32_16x16x32_bf16(a[i], b[j], acc[i][j], 0, 0, 0);
            }
        }
    }

    // fused epilogue: LN(local), reconstruct vox, new, LN(new), relu, store
    const int q = lane >> 4, l15 = lane & 15;
#pragma unroll
    for (int i = 0; i < 2; ++i) {
#pragma unroll
        for (int r = 0; r < 4; ++r) {
            int p = p0 + (w << 5) + (i << 4) + (q << 2) + r;
            if (p >= N_PTS) continue;
            float lv[8], s = 0.f, ss = 0.f;
#pragma unroll
            for (int j = 0; j < 8; ++j) { float v = acc[i][j][r]; lv[j] = v; s += v; ss += v * v; }
#pragma unroll
            for (int m = 1; m < 16; m <<= 1) { s += __shfl_xor(s, m); ss += __shfl_xor(ss, m); }
            float meanL = s * (1.f / 128.f);
            float rstdL = rsqrtf(ss * (1.f / 128.f) - meanL * meanL + 1e-6f);

            float cnt = counts_v[p];
            bool multi = cnt > 1.5f;
            float invc = 1.f / cnt;
            float cx = (float)coords[p * 3 + 0], cy = (float)coords[p * 3 + 1],
                  cz = (float)coords[p * 3 + 2];
            const float* auxp = aux + (size_t)aux_idx[p] * (3 * INC);

            float nv[8], s2 = 0.f, ss2 = 0.f;
#pragma unroll
            for (int j = 0; j < 8; ++j) {
                int c = (j << 4) + l15;
                float f = F_input[(size_t)p * INC + c];
                float ps = compute_pos(c, cx, cy, cz, w_pos, alpha);
                float sn, cs; sincosf(ps, &sn, &cs);
                float v0, v1, v2;
                if (multi) { v0 = auxp[c] * invc; v1 = auxp[INC + c] * invc; v2 = auxp[2 * INC + c] * invc; }
                else       { v0 = f * cs;         v1 = f * sn;               v2 = f * ps; }
                float nw = v0 * cs + v1 * sn + v2 - f * ps;   // singleton: exact cancel
                nv[j] = nw; s2 += nw; ss2 += nw * nw;
            }
#pragma unroll
            for (int m = 1; m < 16; m <<= 1) { s2 += __shfl_xor(s2, m); ss2 += __shfl_xor(ss2, m); }
            float meanN = s2 * (1.f / 128.f);
            float rstdN = rsqrtf(ss2 * (1.f / 128.f) - meanN * meanN + 1e-6f);
#pragma unroll
            for (int j = 0; j < 8; ++j) {
                int c = (j << 4) + l15;
                float nn = (nv[j] - meanN) * rstdN * g_norm[c] + b_norm[c];
                float ll = (lv[j] - meanL) * rstdL * g_local[c] + b_local[c];
                float o = nn + ll;
                out[(size_t)p * INC + c] = o > 0.f ? o : 0.f;
            }
        }
    }
}

// ---------------- host launcher ---------------------------------------------
extern "C" void kernel_launch(void* const* d_in, const int* in_sizes, int n_in,
                              void* d_out, int out_size, void* d_ws, size_t ws_size,
                              hipStream_t stream) {
    (void)in_sizes; (void)n_in; (void)out_size; (void)ws_size;
    const float* F        = (const float*)d_in[0];
    const int*   coords   = (const int*)d_in[1];
    const int*   nbr      = (const int*)d_in[2];
    const int*   aux_idx  = (const int*)d_in[3];
    const float* counts_v = (const float*)d_in[4];
    /* d_in[5] num_aux unused (aux sized by N upper bound) */
    const float* alpha    = (const float*)d_in[6];
    const float* w_pos    = (const float*)d_in[7];
    const float* w_pre    = (const float*)d_in[8];
    const float* g_pre    = (const float*)d_in[9];
    const float* b_pre    = (const float*)d_in[10];
    const float* w_conv   = (const float*)d_in[11];
    const float* g_local  = (const float*)d_in[12];
    const float* b_local  = (const float*)d_in[13];
    const float* g_norm   = (const float*)d_in[14];
    const float* b_norm   = (const float*)d_in[15];
    float* out = (float*)d_out;

    char* ws = (char*)d_ws;
    __hip_bfloat16* Fb      = (__hip_bfloat16*)(ws + OFF_FB);
    __hip_bfloat16* Wb      = (__hip_bfloat16*)(ws + OFF_WB);
    __hip_bfloat16* Wpre    = (__hip_bfloat16*)(ws + OFF_WPRE);
    float*          F_input = (float*)(ws + OFF_FIN);
    float*          aux     = (float*)(ws + OFF_AUX);

    const int tot_cvt = N_PTS * INC + INC + INC * INC + NSLOT * INC * INC;
    k_convert<<<(tot_cvt + 255) / 256, 256, 0, stream>>>(F, w_pre, w_conv, Fb, Wb, Wpre);
    k_zero_aux<<<(N_PTS + 255) / 256, 256, 0, stream>>>(counts_v, aux_idx, aux);

    const int mt = (N_PTS + 127) / 128;   // 782 M-tiles
    k_pre_gemm<<<mt, 256, 0, stream>>>(Fb, Wpre, coords, counts_v, aux_idx,
                                       w_pos, alpha, g_pre, b_pre, F_input, aux);
    k_conv_gemm<<<mt, 256, 0, stream>>>(Fb, Wb, nbr, F_input, aux, coords, counts_v,
                                        aux_idx, w_pos, alpha, g_local, b_local,
                                        g_norm, b_norm, out);
}

// Round 2
// 762.681 us; speedup vs baseline: 1.0886x; 1.0886x over previous
//
#include <hip/hip_runtime.h>
#include <hip/hip_bf16.h>
#include <stdint.h>

#define N_PTS 100000
#define INC 128
#define NSLOT 27

typedef float f32x4 __attribute__((ext_vector_type(4)));
typedef short bf16x8 __attribute__((ext_vector_type(8)));   // 8 bf16 in 4 VGPRs

// ---------------- workspace layout (bytes, all 16-aligned) ----------------
// Fb     : (N+1)*128 bf16   (row N = zeros, the neighbor-pad row)
// Wb     : 27*128*128 bf16  transposed to [slot][d][c]
// Wpre   : 128*128 bf16     [d][c] (== w_pre as stored)
// F_input: N*128 f32        (LN(F @ w_pre^T))
// aux    : N*384 f32        (segment sums; only multi-count cells touched)
static const size_t OFF_FB   = 0;
static const size_t SZ_FB    = (size_t)(N_PTS + 1) * INC * 2;
static const size_t OFF_WB   = OFF_FB + SZ_FB;
static const size_t SZ_WB    = (size_t)NSLOT * INC * INC * 2;
static const size_t OFF_WPRE = OFF_WB + SZ_WB;
static const size_t SZ_WPRE  = (size_t)INC * INC * 2;
static const size_t OFF_FIN  = OFF_WPRE + SZ_WPRE;
static const size_t SZ_FIN   = (size_t)N_PTS * INC * 4;
static const size_t OFF_AUX  = OFF_FIN + SZ_FIN;

// identical in both kernels so the vox2 - F_input*pos cancellation stays ~exact
__device__ __forceinline__ float compute_pos(int c, float cx, float cy, float cz,
                                             const float* __restrict__ w_pos,
                                             const float* __restrict__ alpha) {
    const float* w = w_pos + c * 3;
    return (cx * w[0] + cy * w[1] + cz * w[2]) * alpha[c];
}

// ---------------- K0: dtype conversions (+ zero pad row, w_conv transpose) --
__global__ __launch_bounds__(256) void k_convert(
        const float* __restrict__ F, const float* __restrict__ w_pre,
        const float* __restrict__ w_conv,
        __hip_bfloat16* __restrict__ Fb, __hip_bfloat16* __restrict__ Wb,
        __hip_bfloat16* __restrict__ Wpre) {
    int i = blockIdx.x * 256 + threadIdx.x;
    const int nF  = N_PTS * INC;
    const int nF1 = nF + INC;
    const int nWp = nF1 + INC * INC;
    const int nWc = nWp + NSLOT * INC * INC;
    if (i < nF)  { Fb[i] = __float2bfloat16(F[i]); return; }
    if (i < nF1) { Fb[i] = __float2bfloat16(0.0f); return; }
    if (i < nWp) { int j = i - nF1; Wpre[j] = __float2bfloat16(w_pre[j]); return; }
    if (i < nWc) {
        int j = i - nWp;
        int k = j / (INC * INC); int rem = j % (INC * INC);
        int d = rem / INC;       int c = rem % INC;
        Wb[j] = __float2bfloat16(w_conv[(size_t)k * INC * INC + (size_t)c * INC + d]);
    }
}

// ---------------- K0b: zero aux only for multi-member coarse cells ----------
__global__ __launch_bounds__(256) void k_zero_aux(
        const float* __restrict__ counts_v, const int* __restrict__ aux_idx,
        float* __restrict__ aux) {
    int p = blockIdx.x * 256 + threadIdx.x;
    if (p >= N_PTS) return;
    if (counts_v[p] > 1.5f) {
        float4* a = (float4*)(aux + (size_t)aux_idx[p] * (3 * INC));
        for (int i = 0; i < (3 * INC) / 4; ++i) a[i] = make_float4(0.f, 0.f, 0.f, 0.f);
    }
}

// ---------------- K1: G = F @ w_pre^T — register-direct, no LDS -------------
__global__ __launch_bounds__(256) void k_pre_gemm(
        const __hip_bfloat16* __restrict__ Fb, const __hip_bfloat16* __restrict__ Wpre,
        const int* __restrict__ coords, const float* __restrict__ counts_v,
        const int* __restrict__ aux_idx, const float* __restrict__ w_pos,
        const float* __restrict__ alpha, const float* __restrict__ g_pre,
        const float* __restrict__ b_pre, float* __restrict__ F_input,
        float* __restrict__ aux) {
    const int tid = threadIdx.x, w = tid >> 6, lane = tid & 63;
    const int q = lane >> 4, l15 = lane & 15;
    const int p0 = blockIdx.x * 128;

    int grow0 = p0 + (w << 5) + l15;       // A row for i=0
    int grow1 = grow0 + 16;                // i=1
    if (grow0 > N_PTS) grow0 = N_PTS;      // zero row
    if (grow1 > N_PTS) grow1 = N_PTS;

    const __hip_bfloat16* A0 = Fb + (size_t)grow0 * INC + q * 8;
    const __hip_bfloat16* A1 = Fb + (size_t)grow1 * INC + q * 8;
    const __hip_bfloat16* Bq = Wpre + (size_t)l15 * INC + q * 8;

    f32x4 acc[2][8];
#pragma unroll
    for (int i = 0; i < 2; ++i)
#pragma unroll
        for (int j = 0; j < 8; ++j) acc[i][j] = (f32x4){0.f, 0.f, 0.f, 0.f};

#pragma unroll
    for (int ks = 0; ks < 4; ++ks) {
        bf16x8 a0 = *(const bf16x8*)(A0 + ks * 32);
        bf16x8 a1 = *(const bf16x8*)(A1 + ks * 32);
        bf16x8 b[8];
#pragma unroll
        for (int j = 0; j < 8; ++j) b[j] = *(const bf16x8*)(Bq + j * 16 * INC + ks * 32);
#pragma unroll
        for (int j = 0; j < 8; ++j) {
            acc[0][j] = __builtin_amdgcn_mfma_f32_16x16x32_bf16(a0, b[j], acc[0][j], 0, 0, 0);
            acc[1][j] = __builtin_amdgcn_mfma_f32_16x16x32_bf16(a1, b[j], acc[1][j], 0, 0, 0);
        }
    }

    // epilogue: LN -> F_input; atomic segment-sum of cat for multi cells
#pragma unroll
    for (int i = 0; i < 2; ++i) {
#pragma unroll
        for (int r = 0; r < 4; ++r) {
            int p = p0 + (w << 5) + (i << 4) + (q << 2) + r;
            if (p >= N_PTS) continue;
            float vj[8], s = 0.f, ss = 0.f;
#pragma unroll
            for (int j = 0; j < 8; ++j) { float v = acc[i][j][r]; vj[j] = v; s += v; ss += v * v; }
#pragma unroll
            for (int m = 1; m < 16; m <<= 1) { s += __shfl_xor(s, m); ss += __shfl_xor(ss, m); }
            float mean = s * (1.f / 128.f);
            float rstd = rsqrtf(ss * (1.f / 128.f) - mean * mean + 1e-6f);
            float cnt = counts_v[p];
            bool multi = cnt > 1.5f;
            float cx = (float)coords[p * 3 + 0], cy = (float)coords[p * 3 + 1],
                  cz = (float)coords[p * 3 + 2];
            float* auxp = aux + (size_t)aux_idx[p] * (3 * INC);
#pragma unroll
            for (int j = 0; j < 8; ++j) {
                int c = (j << 4) + l15;
                float fi = (vj[j] - mean) * rstd * g_pre[c] + b_pre[c];
                F_input[(size_t)p * INC + c] = fi;
                if (multi) {
                    float ps = compute_pos(c, cx, cy, cz, w_pos, alpha);
                    float sn, cs; sincosf(ps, &sn, &cs);
                    atomicAdd(auxp + c,           fi * cs);
                    atomicAdd(auxp + INC + c,     fi * sn);
                    atomicAdd(auxp + 2 * INC + c, fi * ps);
                }
            }
        }
    }
}

// ---------------- K2: 27-slot gathered conv GEMM, register-direct, no LDS,
//                  no barriers in the K-loop; full fused epilogue ------------
__global__ __launch_bounds__(256) void k_conv_gemm(
        const __hip_bfloat16* __restrict__ Fb, const __hip_bfloat16* __restrict__ Wb,
        const int* __restrict__ nbr_idx, const float* __restrict__ F_input,
        const float* __restrict__ aux, const int* __restrict__ coords,
        const float* __restrict__ counts_v, const int* __restrict__ aux_idx,
        const float* __restrict__ w_pos, const float* __restrict__ alpha,
        const float* __restrict__ g_local, const float* __restrict__ b_local,
        const float* __restrict__ g_norm, const float* __restrict__ b_norm,
        float* __restrict__ out) {
    const int tid = threadIdx.x, w = tid >> 6, lane = tid & 63;
    const int q = lane >> 4, l15 = lane & 15;
    const int p0 = blockIdx.x * 128;

    const int grow0 = p0 + (w << 5) + l15;   // M row for i=0 (may be >= N)
    const int grow1 = grow0 + 16;            // i=1
    const bool v0 = grow0 < N_PTS, v1 = grow1 < N_PTS;

    const __hip_bfloat16* Aq = Fb + q * 8;
    const __hip_bfloat16* Bq = Wb + (size_t)l15 * INC + q * 8;

    f32x4 acc[2][8];
#pragma unroll
    for (int i = 0; i < 2; ++i)
#pragma unroll
        for (int j = 0; j < 8; ++j) acc[i][j] = (f32x4){0.f, 0.f, 0.f, 0.f};

    // prefetch slot-0 neighbor rows
    int nr0 = v0 ? nbr_idx[grow0 * NSLOT] : N_PTS;
    int nr1 = v1 ? nbr_idx[grow1 * NSLOT] : N_PTS;

#pragma unroll 1
    for (int slot = 0; slot < NSLOT; ++slot) {
        const int r0 = nr0, r1 = nr1;
        if (slot < NSLOT - 1) {   // prefetch next slot's rows during this slot's math
            nr0 = v0 ? nbr_idx[grow0 * NSLOT + slot + 1] : N_PTS;
            nr1 = v1 ? nbr_idx[grow1 * NSLOT + slot + 1] : N_PTS;
        }
        const __hip_bfloat16* A0 = Aq + (size_t)r0 * INC;
        const __hip_bfloat16* A1 = Aq + (size_t)r1 * INC;
        const __hip_bfloat16* Bs = Bq + (size_t)slot * INC * INC;
#pragma unroll
        for (int ks = 0; ks < 4; ++ks) {
            bf16x8 a0 = *(const bf16x8*)(A0 + ks * 32);
            bf16x8 a1 = *(const bf16x8*)(A1 + ks * 32);
            bf16x8 b[8];
#pragma unroll
            for (int j = 0; j < 8; ++j) b[j] = *(const bf16x8*)(Bs + j * 16 * INC + ks * 32);
#pragma unroll
            for (int j = 0; j < 8; ++j) {
                acc[0][j] = __builtin_amdgcn_mfma_f32_16x16x32_bf16(a0, b[j], acc[0][j], 0, 0, 0);
                acc[1][j] = __builtin_amdgcn_mfma_f32_16x16x32_bf16(a1, b[j], acc[1][j], 0, 0, 0);
            }
        }
    }

    // fused epilogue: LN(local), reconstruct vox, new, LN(new), relu, store
#pragma unroll
    for (int i = 0; i < 2; ++i) {
#pragma unroll
        for (int r = 0; r < 4; ++r) {
            int p = p0 + (w << 5) + (i << 4) + (q << 2) + r;
            if (p >= N_PTS) continue;
            float lv[8], s = 0.f, ss = 0.f;
#pragma unroll
            for (int j = 0; j < 8; ++j) { float v = acc[i][j][r]; lv[j] = v; s += v; ss += v * v; }
#pragma unroll
            for (int m = 1; m < 16; m <<= 1) { s += __shfl_xor(s, m); ss += __shfl_xor(ss, m); }
            float meanL = s * (1.f / 128.f);
            float rstdL = rsqrtf(ss * (1.f / 128.f) - meanL * meanL + 1e-6f);

            float cnt = counts_v[p];
            bool multi = cnt > 1.5f;
            float invc = 1.f / cnt;
            float cx = (float)coords[p * 3 + 0], cy = (float)coords[p * 3 + 1],
                  cz = (float)coords[p * 3 + 2];
            const float* auxp = aux + (size_t)aux_idx[p] * (3 * INC);

            float nv[8], s2 = 0.f, ss2 = 0.f;
#pragma unroll
            for (int j = 0; j < 8; ++j) {
                int c = (j << 4) + l15;
                float f = F_input[(size_t)p * INC + c];
                float ps = compute_pos(c, cx, cy, cz, w_pos, alpha);
                float sn, cs; sincosf(ps, &sn, &cs);
                float vv0, vv1, vv2;
                if (multi) { vv0 = auxp[c] * invc; vv1 = auxp[INC + c] * invc; vv2 = auxp[2 * INC + c] * invc; }
                else       { vv0 = f * cs;         vv1 = f * sn;               vv2 = f * ps; }
                float nw = vv0 * cs + vv1 * sn + vv2 - f * ps;   // singleton: exact cancel
                nv[j] = nw; s2 += nw; ss2 += nw * nw;
            }
#pragma unroll
            for (int m = 1; m < 16; m <<= 1) { s2 += __shfl_xor(s2, m); ss2 += __shfl_xor(ss2, m); }
            float meanN = s2 * (1.f / 128.f);
            float rstdN = rsqrtf(ss2 * (1.f / 128.f) - meanN * meanN + 1e-6f);
#pragma unroll
            for (int j = 0; j < 8; ++j) {
                int c = (j << 4) + l15;
                float nn = (nv[j] - meanN) * rstdN * g_norm[c] + b_norm[c];
                float ll = (lv[j] - meanL) * rstdL * g_local[c] + b_local[c];
                float o = nn + ll;
                out[(size_t)p * INC + c] = o > 0.f ? o : 0.f;
            }
        }
    }
}

// ---------------- host launcher ---------------------------------------------
extern "C" void kernel_launch(void* const* d_in, const int* in_sizes, int n_in,
                              void* d_out, int out_size, void* d_ws, size_t ws_size,
                              hipStream_t stream) {
    (void)in_sizes; (void)n_in; (void)out_size; (void)ws_size;
    const float* F        = (const float*)d_in[0];
    const int*   coords   = (const int*)d_in[1];
    const int*   nbr      = (const int*)d_in[2];
    const int*   aux_idx  = (const int*)d_in[3];
    const float* counts_v = (const float*)d_in[4];
    const float* alpha    = (const float*)d_in[6];
    const float* w_pos    = (const float*)d_in[7];
    const float* w_pre    = (const float*)d_in[8];
    const float* g_pre    = (const float*)d_in[9];
    const float* b_pre    = (const float*)d_in[10];
    const float* w_conv   = (const float*)d_in[11];
    const float* g_local  = (const float*)d_in[12];
    const float* b_local  = (const float*)d_in[13];
    const float* g_norm   = (const float*)d_in[14];
    const float* b_norm   = (const float*)d_in[15];
    float* out = (float*)d_out;

    char* ws = (char*)d_ws;
    __hip_bfloat16* Fb      = (__hip_bfloat16*)(ws + OFF_FB);
    __hip_bfloat16* Wb      = (__hip_bfloat16*)(ws + OFF_WB);
    __hip_bfloat16* Wpre    = (__hip_bfloat16*)(ws + OFF_WPRE);
    float*          F_input = (float*)(ws + OFF_FIN);
    float*          aux     = (float*)(ws + OFF_AUX);

    const int tot_cvt = N_PTS * INC + INC + INC * INC + NSLOT * INC * INC;
    k_convert<<<(tot_cvt + 255) / 256, 256, 0, stream>>>(F, w_pre, w_conv, Fb, Wb, Wpre);
    k_zero_aux<<<(N_PTS + 255) / 256, 256, 0, stream>>>(counts_v, aux_idx, aux);

    const int mt = (N_PTS + 127) / 128;   // 782 M-tiles
    k_pre_gemm<<<mt, 256, 0, stream>>>(Fb, Wpre, coords, counts_v, aux_idx,
                                       w_pos, alpha, g_pre, b_pre, F_input, aux);
    k_conv_gemm<<<mt, 256, 0, stream>>>(Fb, Wb, nbr, F_input, aux, coords, counts_v,
                                        aux_idx, w_pos, alpha, g_local, b_local,
                                        g_norm, b_norm, out);
}

// Round 3
// 642.985 us; speedup vs baseline: 1.2913x; 1.1862x over previous
//
#include <hip/hip_runtime.h>
#include <hip/hip_bf16.h>
#include <stdint.h>

#define N_PTS 100000
#define INC 128
#define NSLOT 27

typedef float f32x4 __attribute__((ext_vector_type(4)));
typedef short bf16x8 __attribute__((ext_vector_type(8)));   // 8 bf16 in 4 VGPRs

// ---------------- workspace layout (bytes, all 16-aligned) ----------------
// Fb     : (N+1)*128 bf16      (row N = zeros, the neighbor-pad row)
// Wp     : 27*4*8*64*8 bf16    w_conv fragment-packed: [slot][ks][j][lane][8]
// Wpre   : 4*8*64*8 bf16       w_pre fragment-packed:  [ks][j][lane][8]
// F_input: N*128 f32           (LN(F @ w_pre^T))
// aux    : N*384 f32           (segment sums; only multi-count cells touched)
static const size_t OFF_FB   = 0;
static const size_t SZ_FB    = (size_t)(N_PTS + 1) * INC * 2;
static const size_t OFF_WB   = OFF_FB + SZ_FB;
static const size_t SZ_WB    = (size_t)NSLOT * INC * INC * 2;
static const size_t OFF_WPRE = OFF_WB + SZ_WB;
static const size_t SZ_WPRE  = (size_t)INC * INC * 2;
static const size_t OFF_FIN  = OFF_WPRE + SZ_WPRE;
static const size_t SZ_FIN   = (size_t)N_PTS * INC * 4;
static const size_t OFF_AUX  = OFF_FIN + SZ_FIN;

// identical in both kernels so the vox2 - F_input*pos cancellation stays ~exact
__device__ __forceinline__ float compute_pos(int c, float cx, float cy, float cz,
                                             const float* __restrict__ w_pos,
                                             const float* __restrict__ alpha) {
    const float* w = w_pos + c * 3;
    return (cx * w[0] + cy * w[1] + cz * w[2]) * alpha[c];
}

// ---------------- K0: conversions + fragment packing ------------------------
// B-fragment packing: lane (q=lane>>4, l15=lane&15) of fragment (slot,ks,j)
// holds B[n=j*16+l15][k=ks*32+q*8+i], i=0..7. Packed contiguously so one
// wave-load of a fragment is a single coalesced 1KB burst.
__global__ __launch_bounds__(256) void k_convert(
        const float* __restrict__ F, const float* __restrict__ w_pre,
        const float* __restrict__ w_conv,
        __hip_bfloat16* __restrict__ Fb, __hip_bfloat16* __restrict__ Wp,
        __hip_bfloat16* __restrict__ Wpre) {
    int i = blockIdx.x * 256 + threadIdx.x;
    const int nF  = N_PTS * INC;
    const int nF1 = nF + INC;
    const int nWp = nF1 + INC * INC;
    const int nWc = nWp + NSLOT * INC * INC;
    if (i < nF)  { Fb[i] = __float2bfloat16(F[i]); return; }
    if (i < nF1) { Fb[i] = __float2bfloat16(0.0f); return; }
    if (i < nWp) {           // w_pre packed: out[n=d][k=c] = w_pre[d][c]
        int j = i - nF1;
        int ii = j & 7, lane = (j >> 3) & 63, jj = (j >> 9) & 7, ks = (j >> 12) & 3;
        int l15 = lane & 15, qq = lane >> 4;
        int d = jj * 16 + l15, c = ks * 32 + qq * 8 + ii;
        Wpre[j] = __float2bfloat16(w_pre[d * INC + c]);
        return;
    }
    if (i < nWc) {           // w_conv packed: out[n=d][k=c] = w_conv[slot][c][d]
        int j = i - nWp;
        int ii = j & 7, lane = (j >> 3) & 63, jj = (j >> 9) & 7, ks = (j >> 12) & 3;
        int slot = j >> 14;
        int l15 = lane & 15, qq = lane >> 4;
        int c = ks * 32 + qq * 8 + ii, d = jj * 16 + l15;
        Wp[j] = __float2bfloat16(w_conv[(size_t)slot * INC * INC + (size_t)c * INC + d]);
    }
}

// ---------------- K0b: zero aux only for multi-member coarse cells ----------
__global__ __launch_bounds__(256) void k_zero_aux(
        const float* __restrict__ counts_v, const int* __restrict__ aux_idx,
        float* __restrict__ aux) {
    int p = blockIdx.x * 256 + threadIdx.x;
    if (p >= N_PTS) return;
    if (counts_v[p] > 1.5f) {
        float4* a = (float4*)(aux + (size_t)aux_idx[p] * (3 * INC));
        for (int i = 0; i < (3 * INC) / 4; ++i) a[i] = make_float4(0.f, 0.f, 0.f, 0.f);
    }
}

// ---------------- K1: G = F @ w_pre^T — register-direct, packed B -----------
__global__ __launch_bounds__(256) void k_pre_gemm(
        const __hip_bfloat16* __restrict__ Fb, const __hip_bfloat16* __restrict__ Wpre,
        const int* __restrict__ coords, const float* __restrict__ counts_v,
        const int* __restrict__ aux_idx, const float* __restrict__ w_pos,
        const float* __restrict__ alpha, const float* __restrict__ g_pre,
        const float* __restrict__ b_pre, float* __restrict__ F_input,
        float* __restrict__ aux) {
    const int tid = threadIdx.x, w = tid >> 6, lane = tid & 63;
    const int q = lane >> 4, l15 = lane & 15;
    const int p0 = blockIdx.x * 128;

    int grow0 = p0 + (w << 5) + l15;
    int grow1 = grow0 + 16;
    if (grow0 > N_PTS) grow0 = N_PTS;
    if (grow1 > N_PTS) grow1 = N_PTS;

    const __hip_bfloat16* A0 = Fb + (size_t)grow0 * INC + q * 8;
    const __hip_bfloat16* A1 = Fb + (size_t)grow1 * INC + q * 8;
    const bf16x8* Bp = (const bf16x8*)Wpre;

    f32x4 acc[2][8];
#pragma unroll
    for (int i = 0; i < 2; ++i)
#pragma unroll
        for (int j = 0; j < 8; ++j) acc[i][j] = (f32x4){0.f, 0.f, 0.f, 0.f};

#pragma unroll
    for (int ks = 0; ks < 4; ++ks) {
        bf16x8 a0 = *(const bf16x8*)(A0 + ks * 32);
        bf16x8 a1 = *(const bf16x8*)(A1 + ks * 32);
        bf16x8 b[8];
#pragma unroll
        for (int j = 0; j < 8; ++j) b[j] = Bp[(ks * 8 + j) * 64 + lane];
#pragma unroll
        for (int j = 0; j < 8; ++j) {
            acc[0][j] = __builtin_amdgcn_mfma_f32_16x16x32_bf16(a0, b[j], acc[0][j], 0, 0, 0);
            acc[1][j] = __builtin_amdgcn_mfma_f32_16x16x32_bf16(a1, b[j], acc[1][j], 0, 0, 0);
        }
    }

    // epilogue: LN -> F_input; atomic segment-sum of cat for multi cells
#pragma unroll
    for (int i = 0; i < 2; ++i) {
#pragma unroll
        for (int r = 0; r < 4; ++r) {
            int p = p0 + (w << 5) + (i << 4) + (q << 2) + r;
            if (p >= N_PTS) continue;
            float vj[8], s = 0.f, ss = 0.f;
#pragma unroll
            for (int j = 0; j < 8; ++j) { float v = acc[i][j][r]; vj[j] = v; s += v; ss += v * v; }
#pragma unroll
            for (int m = 1; m < 16; m <<= 1) { s += __shfl_xor(s, m); ss += __shfl_xor(ss, m); }
            float mean = s * (1.f / 128.f);
            float rstd = rsqrtf(ss * (1.f / 128.f) - mean * mean + 1e-6f);
            float cnt = counts_v[p];
            bool multi = cnt > 1.5f;
            float cx = (float)coords[p * 3 + 0], cy = (float)coords[p * 3 + 1],
                  cz = (float)coords[p * 3 + 2];
            float* auxp = aux + (size_t)aux_idx[p] * (3 * INC);
#pragma unroll
            for (int j = 0; j < 8; ++j) {
                int c = (j << 4) + l15;
                float fi = (vj[j] - mean) * rstd * g_pre[c] + b_pre[c];
                F_input[(size_t)p * INC + c] = fi;
                if (multi) {
                    float ps = compute_pos(c, cx, cy, cz, w_pos, alpha);
                    float sn, cs; sincosf(ps, &sn, &cs);
                    atomicAdd(auxp + c,           fi * cs);
                    atomicAdd(auxp + INC + c,     fi * sn);
                    atomicAdd(auxp + 2 * INC + c, fi * ps);
                }
            }
        }
    }
}

// ---------------- K2: conv GEMM, M=64/wave, packed B, no LDS/barriers -------
__global__ __launch_bounds__(128) void k_conv_gemm(
        const __hip_bfloat16* __restrict__ Fb, const __hip_bfloat16* __restrict__ Wp,
        const int* __restrict__ nbr_idx, const float* __restrict__ F_input,
        const float* __restrict__ aux, const int* __restrict__ coords,
        const float* __restrict__ counts_v, const int* __restrict__ aux_idx,
        const float* __restrict__ w_pos, const float* __restrict__ alpha,
        const float* __restrict__ g_local, const float* __restrict__ b_local,
        const float* __restrict__ g_norm, const float* __restrict__ b_norm,
        float* __restrict__ out) {
    const int tid = threadIdx.x, w = tid >> 6, lane = tid & 63;
    const int q = lane >> 4, l15 = lane & 15;
    const int p0 = blockIdx.x * 128 + w * 64;   // this wave's 64 rows

    int growr[4]; bool vld[4];
#pragma unroll
    for (int i = 0; i < 4; ++i) {
        growr[i] = p0 + i * 16 + l15;
        vld[i] = growr[i] < N_PTS;
    }

    const bf16x8* Bp = (const bf16x8*)Wp;

    f32x4 acc[4][8];
#pragma unroll
    for (int i = 0; i < 4; ++i)
#pragma unroll
        for (int j = 0; j < 8; ++j) acc[i][j] = (f32x4){0.f, 0.f, 0.f, 0.f};

    int nr[4];
#pragma unroll
    for (int i = 0; i < 4; ++i) nr[i] = vld[i] ? nbr_idx[growr[i] * NSLOT] : N_PTS;

#pragma unroll 1
    for (int slot = 0; slot < NSLOT; ++slot) {
        int r[4];
#pragma unroll
        for (int i = 0; i < 4; ++i) r[i] = nr[i];
        if (slot < NSLOT - 1) {   // prefetch next slot's neighbor indices
#pragma unroll
            for (int i = 0; i < 4; ++i)
                nr[i] = vld[i] ? nbr_idx[growr[i] * NSLOT + slot + 1] : N_PTS;
        }
        const bf16x8* Bslot = Bp + (size_t)slot * 4 * 8 * 64;
#pragma unroll
        for (int ks = 0; ks < 4; ++ks) {
            bf16x8 a[4];
#pragma unroll
            for (int i = 0; i < 4; ++i)
                a[i] = *(const bf16x8*)(Fb + (size_t)r[i] * INC + ks * 32 + q * 8);
            bf16x8 b[8];
#pragma unroll
            for (int j = 0; j < 8; ++j) b[j] = Bslot[(ks * 8 + j) * 64 + lane];
#pragma unroll
            for (int j = 0; j < 8; ++j)
#pragma unroll
                for (int i = 0; i < 4; ++i)
                    acc[i][j] = __builtin_amdgcn_mfma_f32_16x16x32_bf16(a[i], b[j], acc[i][j], 0, 0, 0);
        }
    }

    // fused epilogue: LN(local), reconstruct vox, new, LN(new), relu, store
#pragma unroll 1
    for (int i = 0; i < 4; ++i) {
#pragma unroll
        for (int r = 0; r < 4; ++r) {
            int p = p0 + i * 16 + (q << 2) + r;
            if (p >= N_PTS) continue;
            float lv[8], s = 0.f, ss = 0.f;
#pragma unroll
            for (int j = 0; j < 8; ++j) { float v = acc[i][j][r]; lv[j] = v; s += v; ss += v * v; }
#pragma unroll
            for (int m = 1; m < 16; m <<= 1) { s += __shfl_xor(s, m); ss += __shfl_xor(ss, m); }
            float meanL = s * (1.f / 128.f);
            float rstdL = rsqrtf(ss * (1.f / 128.f) - meanL * meanL + 1e-6f);

            float cnt = counts_v[p];
            bool multi = cnt > 1.5f;
            float invc = 1.f / cnt;
            float cx = (float)coords[p * 3 + 0], cy = (float)coords[p * 3 + 1],
                  cz = (float)coords[p * 3 + 2];
            const float* auxp = aux + (size_t)aux_idx[p] * (3 * INC);

            float nv[8], s2 = 0.f, ss2 = 0.f;
#pragma unroll
            for (int j = 0; j < 8; ++j) {
                int c = (j << 4) + l15;
                float f = F_input[(size_t)p * INC + c];
                float ps = compute_pos(c, cx, cy, cz, w_pos, alpha);
                float sn, cs; sincosf(ps, &sn, &cs);
                float vv0, vv1, vv2;
                if (multi) { vv0 = auxp[c] * invc; vv1 = auxp[INC + c] * invc; vv2 = auxp[2 * INC + c] * invc; }
                else       { vv0 = f * cs;         vv1 = f * sn;               vv2 = f * ps; }
                float nw = vv0 * cs + vv1 * sn + vv2 - f * ps;   // singleton: exact cancel
                nv[j] = nw; s2 += nw; ss2 += nw * nw;
            }
#pragma unroll
            for (int m = 1; m < 16; m <<= 1) { s2 += __shfl_xor(s2, m); ss2 += __shfl_xor(ss2, m); }
            float meanN = s2 * (1.f / 128.f);
            float rstdN = rsqrtf(ss2 * (1.f / 128.f) - meanN * meanN + 1e-6f);
#pragma unroll
            for (int j = 0; j < 8; ++j) {
                int c = (j << 4) + l15;
                float nn = (nv[j] - meanN) * rstdN * g_norm[c] + b_norm[c];
                float ll = (lv[j] - meanL) * rstdL * g_local[c] + b_local[c];
                float o = nn + ll;
                out[(size_t)p * INC + c] = o > 0.f ? o : 0.f;
            }
        }
    }
}

// ---------------- host launcher ---------------------------------------------
extern "C" void kernel_launch(void* const* d_in, const int* in_sizes, int n_in,
                              void* d_out, int out_size, void* d_ws, size_t ws_size,
                              hipStream_t stream) {
    (void)in_sizes; (void)n_in; (void)out_size; (void)ws_size;
    const float* F        = (const float*)d_in[0];
    const int*   coords   = (const int*)d_in[1];
    const int*   nbr      = (const int*)d_in[2];
    const int*   aux_idx  = (const int*)d_in[3];
    const float* counts_v = (const float*)d_in[4];
    const float* alpha    = (const float*)d_in[6];
    const float* w_pos    = (const float*)d_in[7];
    const float* w_pre    = (const float*)d_in[8];
    const float* g_pre    = (const float*)d_in[9];
    const float* b_pre    = (const float*)d_in[10];
    const float* w_conv   = (const float*)d_in[11];
    const float* g_local  = (const float*)d_in[12];
    const float* b_local  = (const float*)d_in[13];
    const float* g_norm   = (const float*)d_in[14];
    const float* b_norm   = (const float*)d_in[15];
    float* out = (float*)d_out;

    char* ws = (char*)d_ws;
    __hip_bfloat16* Fb      = (__hip_bfloat16*)(ws + OFF_FB);
    __hip_bfloat16* Wp      = (__hip_bfloat16*)(ws + OFF_WB);
    __hip_bfloat16* Wpre    = (__hip_bfloat16*)(ws + OFF_WPRE);
    float*          F_input = (float*)(ws + OFF_FIN);
    float*          aux     = (float*)(ws + OFF_AUX);

    const int tot_cvt = N_PTS * INC + INC + INC * INC + NSLOT * INC * INC;
    k_convert<<<(tot_cvt + 255) / 256, 256, 0, stream>>>(F, w_pre, w_conv, Fb, Wp, Wpre);
    k_zero_aux<<<(N_PTS + 255) / 256, 256, 0, stream>>>(counts_v, aux_idx, aux);

    const int mt = (N_PTS + 127) / 128;   // 782 M-tiles
    k_pre_gemm<<<mt, 256, 0, stream>>>(Fb, Wpre, coords, counts_v, aux_idx,
                                       w_pos, alpha, g_pre, b_pre, F_input, aux);
    k_conv_gemm<<<mt, 128, 0, stream>>>(Fb, Wp, nbr, F_input, aux, coords, counts_v,
                                        aux_idx, w_pos, alpha, g_local, b_local,
                                        g_norm, b_norm, out);
}

// Round 4
// 529.762 us; speedup vs baseline: 1.5673x; 1.2137x over previous
//
#include <hip/hip_runtime.h>
#include <hip/hip_bf16.h>
#include <stdint.h>

#define N_PTS 100000
#define INC 128
#define NSLOT 27
#define CAPP 8192    // pair capacity per slot (expected ~620)
#define CAPA 16384   // compact aux rows (expected ~2100 multi cells)

typedef float f32x4 __attribute__((ext_vector_type(4)));
typedef short bf16x8 __attribute__((ext_vector_type(8)));

// ---------------- workspace layout --------------------------------------
static const size_t OFF_FB   = 0;                                   // (N+1)*128 bf16
static const size_t SZ_FB    = (size_t)(N_PTS + 1) * INC * 2;
static const size_t OFF_WP   = (OFF_FB + SZ_FB + 255) & ~(size_t)255;   // 27 slots frag-packed
static const size_t SZ_WP    = (size_t)NSLOT * INC * INC * 2;
static const size_t OFF_WPRE = (OFF_WP + SZ_WP + 255) & ~(size_t)255;   // w_pre frag-packed
static const size_t SZ_WPRE  = (size_t)INC * INC * 2;
static const size_t OFF_FIN  = (OFF_WPRE + SZ_WPRE + 255) & ~(size_t)255; // F_input f32
static const size_t SZ_FIN   = (size_t)N_PTS * INC * 4;
static const size_t OFF_LOC  = (OFF_FIN + SZ_FIN + 255) & ~(size_t)255;   // local accum f32
static const size_t SZ_LOC   = (size_t)N_PTS * INC * 4;
static const size_t OFF_RMP  = (OFF_LOC + SZ_LOC + 255) & ~(size_t)255;   // cell -> aux id map
static const size_t SZ_RMP   = (size_t)N_PTS * 4;
static const size_t OFF_AUXC = (OFF_RMP + SZ_RMP + 255) & ~(size_t)255;   // compact aux rows
static const size_t SZ_AUXC  = (size_t)CAPA * 3 * INC * 4;
static const size_t OFF_CNT  = (OFF_AUXC + SZ_AUXC + 255) & ~(size_t)255; // 26 pair ctrs + aux ctr
static const size_t SZ_CNT   = 128;
static const size_t OFF_DST  = (OFF_CNT + SZ_CNT + 255) & ~(size_t)255;
static const size_t SZ_DST   = (size_t)26 * CAPP * 4;
static const size_t OFF_SRC  = (OFF_DST + SZ_DST + 255) & ~(size_t)255;
static const size_t SZ_SRC   = (size_t)26 * CAPP * 4;   // total ~156 MB

// identical in all kernels so the vox2 - F_input*pos cancellation stays ~exact
__device__ __forceinline__ float compute_pos(int c, float cx, float cy, float cz,
                                             const float* __restrict__ w_pos,
                                             const float* __restrict__ alpha) {
    const float* w = w_pos + c * 3;
    return (cx * w[0] + cy * w[1] + cz * w[2]) * alpha[c];
}

// ---------------- K_init: zero remap + counters -----------------------------
__global__ __launch_bounds__(256) void k_init(int* __restrict__ rmp, int* __restrict__ cnt) {
    int i = blockIdx.x * 256 + threadIdx.x;
    if (i < N_PTS) rmp[i] = 0;
    if (i < 32) cnt[i] = 0;
}

// ---------------- K_convert: bf16 + fragment packing ------------------------
// Fragment packing: lane (q=lane>>4,l15=lane&15) of frag (slot,ks,j) holds
// B[n=j*16+l15][k=ks*32+q*8+i], i=0..7 -> one wave-load = one 1KB burst.
__global__ __launch_bounds__(256) void k_convert(
        const float* __restrict__ F, const float* __restrict__ w_pre,
        const float* __restrict__ w_conv,
        __hip_bfloat16* __restrict__ Fb, __hip_bfloat16* __restrict__ Wp,
        __hip_bfloat16* __restrict__ Wpre) {
    int i = blockIdx.x * 256 + threadIdx.x;
    const int nF  = N_PTS * INC;
    const int nF1 = nF + INC;
    const int nWp = nF1 + INC * INC;
    const int nWc = nWp + NSLOT * INC * INC;
    if (i < nF)  { Fb[i] = __float2bfloat16(F[i]); return; }
    if (i < nF1) { Fb[i] = __float2bfloat16(0.0f); return; }
    if (i < nWp) {           // w_pre packed: B[n=d][k=c] = w_pre[d][c]
        int j = i - nF1;
        int ii = j & 7, lane = (j >> 3) & 63, jj = (j >> 9) & 7, ks = (j >> 12) & 3;
        int l15 = lane & 15, qq = lane >> 4;
        int d = jj * 16 + l15, c = ks * 32 + qq * 8 + ii;
        Wpre[j] = __float2bfloat16(w_pre[d * INC + c]);
        return;
    }
    if (i < nWc) {           // w_conv packed: B[n=d][k=c] = w_conv[slot][c][d]
        int j = i - nWp;
        int ii = j & 7, lane = (j >> 3) & 63, jj = (j >> 9) & 7, ks = (j >> 12) & 3;
        int slot = j >> 14;
        int l15 = lane & 15, qq = lane >> 4;
        int c = ks * 32 + qq * 8 + ii, d = jj * 16 + l15;
        Wp[j] = __float2bfloat16(w_conv[(size_t)slot * INC * INC + (size_t)c * INC + d]);
    }
}

// ---------------- K_scan: build per-slot pair lists + mark multi cells ------
__global__ __launch_bounds__(256) void k_scan(
        const int* __restrict__ nbr_idx, const float* __restrict__ counts_v,
        const int* __restrict__ aux_idx, int* __restrict__ rmp,
        int* __restrict__ cnt, int* __restrict__ dst, int* __restrict__ src) {
    int p = blockIdx.x * 256 + threadIdx.x;
    if (p >= N_PTS) return;
    if (counts_v[p] > 1.5f) rmp[aux_idx[p]] = 1;   // benign race: all write 1
    const int* nb = nbr_idx + (size_t)p * NSLOT;
#pragma unroll
    for (int k = 0; k < NSLOT; ++k) {
        if (k == 13) continue;                     // self handled densely
        int m = nb[k];
        if (m < N_PTS) {
            int b = k < 13 ? k : k - 1;            // 0..25
            int idx = atomicAdd(&cnt[b], 1);
            if (idx < CAPP) { dst[b * CAPP + idx] = p; src[b * CAPP + idx] = m; }
        }
    }
}

// ---------------- K_assign: compact aux ids + zero their rows ---------------
__global__ __launch_bounds__(256) void k_assign(
        int* __restrict__ rmp, int* __restrict__ cnt, float* __restrict__ auxc) {
    int c = blockIdx.x * 256 + threadIdx.x;
    if (c >= N_PTS) return;
    if (rmp[c] == 1) {
        int id = atomicAdd(&cnt[26], 1);
        if (id < CAPA) {
            rmp[c] = id + 2;
            float4* row = (float4*)(auxc + (size_t)id * (3 * INC));
#pragma unroll
            for (int i = 0; i < (3 * INC) / 4; ++i) row[i] = make_float4(0.f, 0.f, 0.f, 0.f);
        } else rmp[c] = 0;
    }
}

// ---------------- K1: fused dual GEMM: pre_mix + dense self-slot conv -------
__global__ __launch_bounds__(256) void k_pre_gemm(
        const __hip_bfloat16* __restrict__ Fb, const __hip_bfloat16* __restrict__ Wpre,
        const __hip_bfloat16* __restrict__ Wp, const int* __restrict__ coords,
        const float* __restrict__ counts_v, const int* __restrict__ aux_idx,
        const int* __restrict__ rmp, const float* __restrict__ w_pos,
        const float* __restrict__ alpha, const float* __restrict__ g_pre,
        const float* __restrict__ b_pre, float* __restrict__ F_input,
        float* __restrict__ loc, float* __restrict__ auxc) {
    const int tid = threadIdx.x, w = tid >> 6, lane = tid & 63;
    const int q = lane >> 4, l15 = lane & 15;
    const int p0 = blockIdx.x * 128;

    int grow0 = p0 + (w << 5) + l15;
    int grow1 = grow0 + 16;
    if (grow0 > N_PTS) grow0 = N_PTS;
    if (grow1 > N_PTS) grow1 = N_PTS;

    const __hip_bfloat16* A0 = Fb + (size_t)grow0 * INC + q * 8;
    const __hip_bfloat16* A1 = Fb + (size_t)grow1 * INC + q * 8;
    const bf16x8* BpP = (const bf16x8*)Wpre;
    const bf16x8* BpL = (const bf16x8*)Wp + (size_t)13 * 2048;   // self slot

    f32x4 accP[2][8], accL[2][8];
#pragma unroll
    for (int i = 0; i < 2; ++i)
#pragma unroll
        for (int j = 0; j < 8; ++j) {
            accP[i][j] = (f32x4){0.f, 0.f, 0.f, 0.f};
            accL[i][j] = (f32x4){0.f, 0.f, 0.f, 0.f};
        }

#pragma unroll
    for (int ks = 0; ks < 4; ++ks) {
        bf16x8 a0 = *(const bf16x8*)(A0 + ks * 32);
        bf16x8 a1 = *(const bf16x8*)(A1 + ks * 32);
        bf16x8 bP[8], bL[8];
#pragma unroll
        for (int j = 0; j < 8; ++j) { bP[j] = BpP[(ks * 8 + j) * 64 + lane]; bL[j] = BpL[(ks * 8 + j) * 64 + lane]; }
#pragma unroll
        for (int j = 0; j < 8; ++j) {
            accP[0][j] = __builtin_amdgcn_mfma_f32_16x16x32_bf16(a0, bP[j], accP[0][j], 0, 0, 0);
            accP[1][j] = __builtin_amdgcn_mfma_f32_16x16x32_bf16(a1, bP[j], accP[1][j], 0, 0, 0);
            accL[0][j] = __builtin_amdgcn_mfma_f32_16x16x32_bf16(a0, bL[j], accL[0][j], 0, 0, 0);
            accL[1][j] = __builtin_amdgcn_mfma_f32_16x16x32_bf16(a1, bL[j], accL[1][j], 0, 0, 0);
        }
    }

    // epilogue: LN -> F_input; store self-local to loc; aux atomics (compact)
#pragma unroll
    for (int i = 0; i < 2; ++i) {
#pragma unroll
        for (int r = 0; r < 4; ++r) {
            int p = p0 + (w << 5) + (i << 4) + (q << 2) + r;
            if (p >= N_PTS) continue;
            float vj[8], s = 0.f, ss = 0.f;
#pragma unroll
            for (int j = 0; j < 8; ++j) { float v = accP[i][j][r]; vj[j] = v; s += v; ss += v * v; }
#pragma unroll
            for (int m = 1; m < 16; m <<= 1) { s += __shfl_xor(s, m); ss += __shfl_xor(ss, m); }
            float mean = s * (1.f / 128.f);
            float rstd = rsqrtf(ss * (1.f / 128.f) - mean * mean + 1e-6f);
            int rid = 0;
            bool multi = counts_v[p] > 1.5f && (rid = rmp[aux_idx[p]]) >= 2;
            float cx = (float)coords[p * 3 + 0], cy = (float)coords[p * 3 + 1],
                  cz = (float)coords[p * 3 + 2];
            float* auxp = auxc + (size_t)(rid - 2) * (3 * INC);
#pragma unroll
            for (int j = 0; j < 8; ++j) {
                int c = (j << 4) + l15;
                float fi = (vj[j] - mean) * rstd * g_pre[c] + b_pre[c];
                F_input[(size_t)p * INC + c] = fi;
                loc[(size_t)p * INC + c] = accL[i][j][r];
                if (multi) {
                    float ps = compute_pos(c, cx, cy, cz, w_pos, alpha);
                    float sn, cs; sincosf(ps, &sn, &cs);
                    atomicAdd(auxp + c,           fi * cs);
                    atomicAdd(auxp + INC + c,     fi * sn);
                    atomicAdd(auxp + 2 * INC + c, fi * ps);
                }
            }
        }
    }
}

// ---------------- K_sparse: pair GEMM, scatter-add into loc -----------------
__global__ __launch_bounds__(64) void k_sparse(
        const __hip_bfloat16* __restrict__ Fb, const __hip_bfloat16* __restrict__ Wp,
        const int* __restrict__ cnt, const int* __restrict__ dst,
        const int* __restrict__ src, float* __restrict__ loc) {
    const int b = blockIdx.x >> 7;          // bucket 0..25
    const int chunk = blockIdx.x & 127;
    int n = cnt[b]; if (n > CAPP) n = CAPP;
    const int base = chunk * 64;
    if (base >= n) return;
    const int slot = b < 13 ? b : b + 1;

    const int lane = threadIdx.x & 63;
    const int q = lane >> 4, l15 = lane & 15;
    const int* srcb = src + b * CAPP;
    const int* dstb = dst + b * CAPP;

    int m[4];
#pragma unroll
    for (int i = 0; i < 4; ++i) {
        int ri = base + i * 16 + l15;
        m[i] = (ri < n) ? srcb[ri] : N_PTS;
    }
    const bf16x8* Bp = (const bf16x8*)Wp + (size_t)slot * 2048;

    f32x4 acc[4][8];
#pragma unroll
    for (int i = 0; i < 4; ++i)
#pragma unroll
        for (int j = 0; j < 8; ++j) acc[i][j] = (f32x4){0.f, 0.f, 0.f, 0.f};

#pragma unroll
    for (int ks = 0; ks < 4; ++ks) {
        bf16x8 a[4];
#pragma unroll
        for (int i = 0; i < 4; ++i)
            a[i] = *(const bf16x8*)(Fb + (size_t)m[i] * INC + ks * 32 + q * 8);
        bf16x8 bb[8];
#pragma unroll
        for (int j = 0; j < 8; ++j) bb[j] = Bp[(ks * 8 + j) * 64 + lane];
#pragma unroll
        for (int j = 0; j < 8; ++j)
#pragma unroll
            for (int i = 0; i < 4; ++i)
                acc[i][j] = __builtin_amdgcn_mfma_f32_16x16x32_bf16(a[i], bb[j], acc[i][j], 0, 0, 0);
    }

    // scatter-add rows into loc
#pragma unroll
    for (int i = 0; i < 4; ++i) {
#pragma unroll
        for (int r = 0; r < 4; ++r) {
            int ri = base + i * 16 + (q << 2) + r;
            if (ri >= n) continue;
            int pd = dstb[ri];
            float* lp = loc + (size_t)pd * INC + l15;
#pragma unroll
            for (int j = 0; j < 8; ++j) atomicAdd(lp + (j << 4), acc[i][j][r]);
        }
    }
}

// ---------------- K_final: epilogue only ------------------------------------
__global__ __launch_bounds__(256) void k_final(
        const float* __restrict__ F_input, const float* __restrict__ loc,
        const int* __restrict__ rmp, const float* __restrict__ auxc,
        const int* __restrict__ coords, const float* __restrict__ counts_v,
        const int* __restrict__ aux_idx, const float* __restrict__ w_pos,
        const float* __restrict__ alpha, const float* __restrict__ g_local,
        const float* __restrict__ b_local, const float* __restrict__ g_norm,
        const float* __restrict__ b_norm, float* __restrict__ out) {
    const int tid = threadIdx.x, g = tid >> 4, l15 = tid & 15;
    const int p0 = blockIdx.x * 128;
#pragma unroll 1
    for (int t = 0; t < 8; ++t) {
        int p = p0 + t * 16 + g;
        if (p >= N_PTS) continue;
        float lv[8], s = 0.f, ss = 0.f;
#pragma unroll
        for (int j = 0; j < 8; ++j) {
            float v = loc[(size_t)p * INC + (j << 4) + l15];
            lv[j] = v; s += v; ss += v * v;
        }
#pragma unroll
        for (int m = 1; m < 16; m <<= 1) { s += __shfl_xor(s, m); ss += __shfl_xor(ss, m); }
        float meanL = s * (1.f / 128.f);
        float rstdL = rsqrtf(ss * (1.f / 128.f) - meanL * meanL + 1e-6f);

        float cnt = counts_v[p];
        int rid = 0;
        bool multi = cnt > 1.5f && (rid = rmp[aux_idx[p]]) >= 2;
        float invc = 1.f / cnt;
        float cx = (float)coords[p * 3 + 0], cy = (float)coords[p * 3 + 1],
              cz = (float)coords[p * 3 + 2];
        const float* auxp = auxc + (size_t)(rid - 2) * (3 * INC);

        float nv[8], s2 = 0.f, ss2 = 0.f;
#pragma unroll
        for (int j = 0; j < 8; ++j) {
            int c = (j << 4) + l15;
            float f = F_input[(size_t)p * INC + c];
            float ps = compute_pos(c, cx, cy, cz, w_pos, alpha);
            float sn, cs; sincosf(ps, &sn, &cs);
            float v0, v1, v2;
            if (multi) { v0 = auxp[c] * invc; v1 = auxp[INC + c] * invc; v2 = auxp[2 * INC + c] * invc; }
            else       { v0 = f * cs;         v1 = f * sn;               v2 = f * ps; }
            float nw = v0 * cs + v1 * sn + v2 - f * ps;   // singleton: exact cancel
            nv[j] = nw; s2 += nw; ss2 += nw * nw;
        }
#pragma unroll
        for (int m = 1; m < 16; m <<= 1) { s2 += __shfl_xor(s2, m); ss2 += __shfl_xor(ss2, m); }
        float meanN = s2 * (1.f / 128.f);
        float rstdN = rsqrtf(ss2 * (1.f / 128.f) - meanN * meanN + 1e-6f);
#pragma unroll
        for (int j = 0; j < 8; ++j) {
            int c = (j << 4) + l15;
            float nn = (nv[j] - meanN) * rstdN * g_norm[c] + b_norm[c];
            float ll = (lv[j] - meanL) * rstdL * g_local[c] + b_local[c];
            float o = nn + ll;
            out[(size_t)p * INC + c] = o > 0.f ? o : 0.f;
        }
    }
}

// ---------------- host launcher ---------------------------------------------
extern "C" void kernel_launch(void* const* d_in, const int* in_sizes, int n_in,
                              void* d_out, int out_size, void* d_ws, size_t ws_size,
                              hipStream_t stream) {
    (void)in_sizes; (void)n_in; (void)out_size; (void)ws_size;
    const float* F        = (const float*)d_in[0];
    const int*   coords   = (const int*)d_in[1];
    const int*   nbr      = (const int*)d_in[2];
    const int*   aux_idx  = (const int*)d_in[3];
    const float* counts_v = (const float*)d_in[4];
    const float* alpha    = (const float*)d_in[6];
    const float* w_pos    = (const float*)d_in[7];
    const float* w_pre    = (const float*)d_in[8];
    const float* g_pre    = (const float*)d_in[9];
    const float* b_pre    = (const float*)d_in[10];
    const float* w_conv   = (const float*)d_in[11];
    const float* g_local  = (const float*)d_in[12];
    const float* b_local  = (const float*)d_in[13];
    const float* g_norm   = (const float*)d_in[14];
    const float* b_norm   = (const float*)d_in[15];
    float* out = (float*)d_out;

    char* ws = (char*)d_ws;
    __hip_bfloat16* Fb   = (__hip_bfloat16*)(ws + OFF_FB);
    __hip_bfloat16* Wp   = (__hip_bfloat16*)(ws + OFF_WP);
    __hip_bfloat16* Wpre = (__hip_bfloat16*)(ws + OFF_WPRE);
    float* F_input = (float*)(ws + OFF_FIN);
    float* loc     = (float*)(ws + OFF_LOC);
    int*   rmp     = (int*)(ws + OFF_RMP);
    float* auxc    = (float*)(ws + OFF_AUXC);
    int*   cnt     = (int*)(ws + OFF_CNT);
    int*   dstb    = (int*)(ws + OFF_DST);
    int*   srcb    = (int*)(ws + OFF_SRC);

    const int mt = (N_PTS + 127) / 128;   // 782
    k_init<<<(N_PTS + 255) / 256, 256, 0, stream>>>(rmp, cnt);
    const int tot_cvt = N_PTS * INC + INC + INC * INC + NSLOT * INC * INC;
    k_convert<<<(tot_cvt + 255) / 256, 256, 0, stream>>>(F, w_pre, w_conv, Fb, Wp, Wpre);
    k_scan<<<(N_PTS + 255) / 256, 256, 0, stream>>>(nbr, counts_v, aux_idx, rmp, cnt, dstb, srcb);
    k_assign<<<(N_PTS + 255) / 256, 256, 0, stream>>>(rmp, cnt, auxc);
    k_pre_gemm<<<mt, 256, 0, stream>>>(Fb, Wpre, Wp, coords, counts_v, aux_idx, rmp,
                                       w_pos, alpha, g_pre, b_pre, F_input, loc, auxc);
    k_sparse<<<26 * 128, 64, 0, stream>>>(Fb, Wp, cnt, dstb, srcb, loc);
    k_final<<<mt, 256, 0, stream>>>(F_input, loc, rmp, auxc, coords, counts_v, aux_idx,
                                    w_pos, alpha, g_local, b_local, g_norm, b_norm, out);
}